// Round 13
// baseline (89.626 us; speedup 1.0000x reference)
//
#include <hip/hip_runtime.h>

#define Bb 4
#define Cc 256
#define GC_ 64
#define Hh 128
#define Wd 128
#define HWn 16384
#define NPIX 65536
#define EPS 1e-5f

// workspace layout (float offsets). T region holds t (bf16) then xbf (bf16).
#define T_OFF   0
#define E_OFF   16777216
#define ST_OFF  (E_OFF + NPIX*4)
#define A_OFF   (ST_OFF + 16)      // Abf: 16384 u16 = 32KB, fragment-packed
#define CV_OFF  (A_OFF + 16384)
#define FW_OFF  (CV_OFF + 256)

typedef __attribute__((ext_vector_type(8))) short short8v;
typedef __attribute__((ext_vector_type(4))) float f32x4;
typedef unsigned short u16;

__device__ inline u16 f2bf(float f) {
    union { float f; unsigned u; } v; v.f = f;
    unsigned r = v.u + 0x7fff + ((v.u >> 16) & 1);   // RNE
    return (u16)(r >> 16);
}
__device__ inline float bf2f(u16 u) {
    union { unsigned u; float f; } v; v.u = ((unsigned)u) << 16;
    return v.f;
}

// K0: Abf_g = bf16(qw_g^T @ kw_g) fragment-packed; cvec; fwred; zero stats.
__global__ __launch_bounds__(256) void k0_precompute(
    const float* __restrict__ qw, const float* __restrict__ kw,
    const float* __restrict__ rk0, const float* __restrict__ rk1,
    const float* __restrict__ rk2, const float* __restrict__ rk3,
    const float* __restrict__ fusion_w,
    u16* __restrict__ Abf, float* __restrict__ cvec, float* __restrict__ fwred,
    float* __restrict__ stats)
{
    const int tid = threadIdx.x;
    if (blockIdx.x == 4) {
        if (tid < 16) stats[tid] = 0.f;
        for (int i = 0; i < 4; ++i) {
            float s = 0.f;
            const float* fp = fusion_w + tid*256 + i*64;
            #pragma unroll 8
            for (int c = 0; c < 64; ++c) s += fp[c];
            fwred[tid*4 + i] = s;
        }
        return;
    }
    const int g = blockIdx.x;
    __shared__ float qwL[4096];
    __shared__ float kwL[4096];
    __shared__ float rks[64];
    for (int i = tid; i < 4096; i += 256) {
        qwL[i] = qw[g*4096 + i];
        kwL[i] = kw[g*4096 + i];
    }
    __syncthreads();
    if (tid < 64) {
        const float* rkp = (g==0)?rk0:(g==1)?rk1:(g==2)?rk2:rk3;
        const int R = 4*g + 9;               // 2L-1 for L={5,7,9,11}
        float s = 0.f;
        for (int r = 0; r < R; ++r) s += rkp[tid*R + r];
        rks[tid] = s;
    }
    __syncthreads();
    for (int idx = tid; idx < 4096; idx += 256) {
        const int ct = idx >> 10, kh = (idx >> 9) & 1;
        const int lane = (idx >> 3) & 63, j = idx & 7;
        const int c = ct*16 + (lane & 15);
        const int d = kh*32 + (lane >> 4)*8 + j;
        float s = 0.f;
        #pragma unroll
        for (int o = 0; o < 64; ++o) s += qwL[o*64 + c] * kwL[o*64 + d];
        Abf[g*4096 + idx] = f2bf(s);
    }
    if (tid < 64) {
        float s = 0.f;
        #pragma unroll
        for (int o = 0; o < 64; ++o) s += qwL[o*64 + tid] * rks[o];
        cvec[g*64 + tid] = s;
    }
}

// K1 v5 (MFMA, barrier-free): t = A_g x (bf16), xbf = bf16(x).
// Each wave stages ITS OWN 64px x 64ch x-slice into a wave-private LDS region
// (wave-coherent lgkmcnt ordering only, NO __syncthreads) -> 16 free-running
// waves/CU hide HBM latency. 256 px/block, grid 1024, LDS 34.8KB -> 4 blocks/CU.
__global__ __launch_bounds__(256) void k1_mfma(
    const float* __restrict__ x, const u16* __restrict__ Abf,
    u16* __restrict__ t, u16* __restrict__ xbf)
{
    __shared__ u16 xt[4][64*68];       // per-wave region, row stride 68 u16
    const int tid = threadIdx.x;
    const int wv = tid >> 6, lane = tid & 63;
    const int chunk = blockIdx.x & 63;
    const int g = (blockIdx.x >> 6) & 3;
    const int b = blockIdx.x >> 8;
    const int l15 = lane & 15, lg = lane >> 4;
    const int px0w = chunk*256 + wv*64;      // wave's 64-px window

    // A-fragments: 8 coalesced 16B loads from prepacked Abf
    const u16* Ab = Abf + g*4096;
    short8v afr[4][2];
    #pragma unroll
    for (int ct = 0; ct < 4; ++ct)
      #pragma unroll
      for (int kh = 0; kh < 2; ++kh)
        afr[ct][kh] = *(const short8v*)(Ab + ((ct*2 + kh)*64 + lane)*8);

    const float* xg = x   + (size_t)(b*Cc + g*GC_)*HWn;
    u16* tg        = t    + (size_t)(b*Cc + g*GC_)*HWn;
    u16* xbg       = xbf  + (size_t)(b*Cc + g*GC_)*HWn;
    u16* xw = &xt[wv][0];

    // wave-private stage: 64ch x 64px, float4 loads -> bf16 -> LDS + xbf
    const int pxo = l15 << 2;
    #pragma unroll
    for (int i = 0; i < 16; ++i) {
        const int ch = i*4 + lg;
        const float4 v = *(const float4*)(xg + (size_t)ch*HWn + px0w + pxo);
        u16 o4[4] __attribute__((aligned(8))) = {f2bf(v.x), f2bf(v.y), f2bf(v.z), f2bf(v.w)};
        *(uint2*)(xw + ch*68 + pxo) = *(const uint2*)o4;
        *(uint2*)(xbg + (size_t)ch*HWn + px0w + pxo) = *(const uint2*)o4;
    }
    // no __syncthreads: wave reads only its own region; compiler orders via lgkmcnt

    #pragma unroll
    for (int nt = 0; nt < 2; ++nt) {
        const int pt = nt*32 + ((lane & 1) << 4) + l15;   // dummy? no — see below
        (void)pt;
        const int px = nt*16 + l15;                        // fragment px within window... 
        short8v bfr[2];
        #pragma unroll
        for (int kh = 0; kh < 2; ++kh)
          #pragma unroll
          for (int j = 0; j < 8; ++j)
            bfr[kh][j] = (short)xw[(kh*32 + lg*8 + j)*68 + px];
        #pragma unroll
        for (int ct = 0; ct < 4; ++ct) {
            f32x4 acc = {0.f, 0.f, 0.f, 0.f};
            acc = __builtin_amdgcn_mfma_f32_16x16x32_bf16(bfr[0], afr[ct][0], acc, 0, 0, 0);
            acc = __builtin_amdgcn_mfma_f32_16x16x32_bf16(bfr[1], afr[ct][1], acc, 0, 0, 0);
            u16 ov[4] __attribute__((aligned(8)));
            #pragma unroll
            for (int r = 0; r < 4; ++r) ov[r] = f2bf(acc[r]);
            *(uint2*)(tg + (size_t)(ct*16 + l15)*HWn + px0w + nt*16 + lg*4) = *(const uint2*)ov;
        }
    }
    // NOTE: waves 2,3 window covers px0w..px0w+63; nt covers first 32 px via
    // nt*16+l15 (0..31)... second half handled below.
    #pragma unroll
    for (int nt = 2; nt < 4; ++nt) {
        const int px = nt*16 + l15;                        // 32..63
        short8v bfr[2];
        #pragma unroll
        for (int kh = 0; kh < 2; ++kh)
          #pragma unroll
          for (int j = 0; j < 8; ++j)
            bfr[kh][j] = (short)xw[(kh*32 + lg*8 + j)*68 + px];
        #pragma unroll
        for (int ct = 0; ct < 4; ++ct) {
            f32x4 acc = {0.f, 0.f, 0.f, 0.f};
            acc = __builtin_amdgcn_mfma_f32_16x16x32_bf16(bfr[0], afr[ct][0], acc, 0, 0, 0);
            acc = __builtin_amdgcn_mfma_f32_16x16x32_bf16(bfr[1], afr[ct][1], acc, 0, 0, 0);
            u16 ov[4] __attribute__((aligned(8)));
            #pragma unroll
            for (int r = 0; r < 4; ++r) ov[r] = f2bf(acc[r]);
            *(uint2*)(tg + (size_t)(ct*16 + l15)*HWn + px0w + nt*16 + lg*4) = *(const uint2*)ov;
        }
    }
}

// K23 v4: fused cross-sum + e accumulation; 16 channels/block, 8-row tiles.
// Grid 1024 (4 blocks/CU, fully resident). Partial e planes stored bf16.
__global__ __launch_bounds__(256) void k23_fused(
    const u16* __restrict__ t, const u16* __restrict__ xbf,
    const float* __restrict__ r_q, const float* __restrict__ cvec,
    u16* __restrict__ eh)
{
    __shared__ u16 timg[4][18*132];     // 2 live + 2 prefetch-dest; fixed 18 rows staged
    __shared__ u16 simg[2][8*132];
    __shared__ float rqL[16], cvL[16];
    const int tid = threadIdx.x;
    const int bid = blockIdx.x;
    const int wk = (bid & 7)*128 + (bid >> 3);   // 1024 = 8*128, bijective
    const int qh = wk & 3;               // 16-channel group
    const int htile = (wk >> 2) & 15;    // 8 rows
    const int g = (wk >> 6) & 3;
    const int b = wk >> 8;
    const int p = g + 2;                 // pad {2,3,4,5}
    const int h0 = htile*8;
    const int c0 = qh*16;

    if (tid < 16) { rqL[tid] = r_q[g*64 + c0 + tid]; cvL[tid] = cvec[g*64 + c0 + tid]; }

    const u16* tbase = t   + (size_t)(b*Cc + g*GC_ + c0)*HWn;
    const u16* xbase = xbf + (size_t)(b*Cc + g*GC_ + c0)*HWn;

    // stage pair 0: fixed 18 rows per channel (zero-fill OOB; extra rows unused)
    #pragma unroll
    for (int k = 0; k < 3; ++k) {
        const int idx = tid + k*256;
        if (idx < 576) {
            const int r = idx >> 5, w4 = (idx & 31) << 2;
            const int hh = h0 - p + r;
            uint2 v0 = make_uint2(0u,0u), v1 = make_uint2(0u,0u);
            if (hh >= 0 && hh < 128) {
                v0 = *(const uint2*)(tbase + (hh<<7) + w4);
                v1 = *(const uint2*)(tbase + HWn + (hh<<7) + w4);
            }
            *(uint2*)(&timg[0][r*132 + w4]) = v0;
            *(uint2*)(&timg[1][r*132 + w4]) = v1;
        }
    }
    __syncthreads();

    // fixed per-thread mappings
    const int vch = tid >> 7, vcol = tid & 127;                      // vertical
    const int hch = tid >> 7, hr = (tid & 127) >> 4, hseg = tid & 15, hw0 = hseg*8; // horizontal
    float er[8];
    #pragma unroll
    for (int j = 0; j < 8; ++j) er[j] = 0.f;

    for (int it = 0; it < 8; ++it) {
        const int curp = (it & 1)*2;
        // prefetch next pair into regs (static indices)
        uint2 pr0[3], pr1[3];
        if (it < 7) {
            const u16* tn0 = tbase + (size_t)(2*it + 2)*HWn;
            const u16* tn1 = tn0 + HWn;
            #pragma unroll
            for (int k = 0; k < 3; ++k) {
                const int idx = tid + k*256;
                pr0[k] = make_uint2(0u,0u); pr1[k] = make_uint2(0u,0u);
                if (idx < 576) {
                    const int r = idx >> 5, w4 = (idx & 31) << 2;
                    const int hh = h0 - p + r;
                    if (hh >= 0 && hh < 128) {
                        pr0[k] = *(const uint2*)(tn0 + (hh<<7) + w4);
                        pr1[k] = *(const uint2*)(tn1 + (hh<<7) + w4);
                    }
                }
            }
        }

        // vertical sliding box: this half's channel, 1 col x 8 rows
        {
            const u16* tb = &timg[curp + vch][0];
            float run = 0.f;
            for (int j = 0; j <= 2*p; ++j) run += bf2f(tb[j*132 + vcol]);
            #pragma unroll
            for (int i = 0; i < 8; ++i) {
                simg[vch][i*132 + vcol] = f2bf(run);
                if (i != 7)
                    run += bf2f(tb[(i + 1 + 2*p)*132 + vcol]) - bf2f(tb[i*132 + vcol]);
            }
        }
        __syncthreads();

        // horizontal sliding + combine + accumulate: 1 row x 8 px per thread
        {
            const int cc = it*2 + hch;
            const u16* trow = &timg[curp + hch][(hr + p)*132];
            float run = 0.f;
            const int lo = max(hw0 - p, 0), hi = min(hw0 + p, 127);
            for (int ww = lo; ww <= hi; ++ww) run += bf2f(trow[ww]);
            const float rq = rqL[cc], cv = cvL[cc];
            union { uint4 q; u16 s[8]; } xu;
            xu.q = *(const uint4*)(xbase + (size_t)cc*HWn + ((h0 + hr) << 7) + hw0);
            #pragma unroll
            for (int j = 0; j < 8; ++j) {
                const int w = hw0 + j;
                const float S = run + bf2f(simg[hch][hr*132 + w]) - bf2f(trow[w]);
                er[j] += (bf2f(xu.s[j]) + rq) * (S + cv);
                run += (w + 1 + p < 128 ? bf2f(trow[w + 1 + p]) : 0.f)
                     - (w - p     >= 0  ? bf2f(trow[w - p])     : 0.f);
            }
        }
        // write prefetched pair into the other buffers
        if (it < 7) {
            const int nxt = curp ^ 2;
            #pragma unroll
            for (int k = 0; k < 3; ++k) {
                const int idx = tid + k*256;
                if (idx < 576) {
                    const int r = idx >> 5, w4 = (idx & 31) << 2;
                    *(uint2*)(&timg[nxt + 0][r*132 + w4]) = pr0[k];
                    *(uint2*)(&timg[nxt + 1][r*132 + w4]) = pr1[k];
                }
            }
        }
        __syncthreads();
    }

    // write partial e plane (qh*2 + hch) as bf16 (8 u16 = one uint4)
    u16 ov[8] __attribute__((aligned(16)));
    #pragma unroll
    for (int j = 0; j < 8; ++j) ov[j] = f2bf(er[j]);
    u16* ep = eh + (size_t)((qh*2 + hch)*16 + b*4 + g)*HWn + ((h0 + hr) << 7) + hw0;
    *(uint4*)ep = *(const uint4*)ov;
}

// K3b: combine 8 bf16 partial planes -> ebuf (f32); 4x4 moment matrix (14 scalars).
__global__ __launch_bounds__(256) void k3b_stats(
    const u16* __restrict__ eh, float* __restrict__ ebuf, float* __restrict__ stats)
{
    __shared__ float red[4*14];
    const int tid = threadIdx.x;
    const int q = blockIdx.x*256 + tid;
    const int b = q >> 14, p = q & (HWn - 1);
    float e4[4];
    #pragma unroll
    for (int g = 0; g < 4; ++g) {
        float s = 0.f;
        #pragma unroll
        for (int qq = 0; qq < 8; ++qq)
            s += bf2f(eh[(size_t)(qq*16 + b*4 + g)*HWn + p]);
        e4[g] = s;
        ebuf[(size_t)(b*4 + g)*HWn + p] = s;
    }
    const float e0 = e4[0], e1 = e4[1], e2 = e4[2], e3 = e4[3];
    float v[14];
    v[0]=e0; v[1]=e1; v[2]=e2; v[3]=e3;
    v[4]=e0*e0; v[5]=e0*e1; v[6]=e0*e2; v[7]=e0*e3;
    v[8]=e1*e1; v[9]=e1*e2; v[10]=e1*e3;
    v[11]=e2*e2; v[12]=e2*e3; v[13]=e3*e3;
    #pragma unroll
    for (int kk = 0; kk < 14; ++kk) {
        float s = v[kk];
        for (int off = 32; off > 0; off >>= 1) s += __shfl_down(s, off, 64);
        v[kk] = s;
    }
    const int lane = tid & 63, wv = tid >> 6;
    if (lane == 0) {
        #pragma unroll
        for (int kk = 0; kk < 14; ++kk) red[wv*14 + kk] = v[kk];
    }
    __syncthreads();
    if (tid < 14) atomicAdd(&stats[tid], red[tid] + red[14+tid] + red[28+tid] + red[42+tid]);
}

// K5: out = x * sigmoid(relu(alpha*(fwred·e)+beta2)); 8 channels/block; BN-fold inline.
__global__ __launch_bounds__(256) void k5_out(
    const u16* __restrict__ xbf, const float* __restrict__ ebuf,
    const float* __restrict__ fwred, const float* __restrict__ stats,
    const float* __restrict__ gamma, const float* __restrict__ beta,
    float* __restrict__ out)
{
    const int tid = threadIdx.x;
    const int chunk = blockIdx.x & 15;
    const int oct = (blockIdx.x >> 4) & 31;
    const int b = blockIdx.x >> 9;
    __shared__ float alL[8], beL[8];
    __shared__ float4 fwL[8];
    if (tid < 8) {
        const int o = oct*8 + tid;
        const float invN = 1.f / (float)NPIX;
        const float me0 = stats[0]*invN, me1 = stats[1]*invN, me2 = stats[2]*invN, me3 = stats[3]*invN;
        const float m00 = stats[4]*invN,  m01 = stats[5]*invN,  m02 = stats[6]*invN,  m03 = stats[7]*invN;
        const float m11 = stats[8]*invN,  m12 = stats[9]*invN,  m13 = stats[10]*invN;
        const float m22 = stats[11]*invN, m23 = stats[12]*invN, m33 = stats[13]*invN;
        const float4 fw = ((const float4*)fwred)[o];
        const float Ef = fw.x*me0 + fw.y*me1 + fw.z*me2 + fw.w*me3;
        const float E2 = fw.x*fw.x*m00 + fw.y*fw.y*m11 + fw.z*fw.z*m22 + fw.w*fw.w*m33
                       + 2.f*(fw.x*fw.y*m01 + fw.x*fw.z*m02 + fw.x*fw.w*m03
                            + fw.y*fw.z*m12 + fw.y*fw.w*m13 + fw.z*fw.w*m23);
        const float a = gamma[o] * rsqrtf(E2 - Ef*Ef + EPS);
        alL[tid] = a;
        beL[tid] = beta[o] - Ef*a;
        fwL[tid] = fw;
    }
    __syncthreads();

    const int p0 = chunk*1024 + tid*4;
    const float* eb = ebuf + (size_t)b*4*HWn;
    const float4 E0 = *(const float4*)(eb + 0*HWn + p0);
    const float4 E1 = *(const float4*)(eb + 1*HWn + p0);
    const float4 E2v = *(const float4*)(eb + 2*HWn + p0);
    const float4 E3 = *(const float4*)(eb + 3*HWn + p0);

    #pragma unroll
    for (int c = 0; c < 8; ++c) {
        const int o = oct*8 + c;
        const float4 fw = fwL[c];
        const float al = alL[c], be = beL[c];
        float f[4];
        f[0] = fw.x*E0.x + fw.y*E1.x + fw.z*E2v.x + fw.w*E3.x;
        f[1] = fw.x*E0.y + fw.y*E1.y + fw.z*E2v.y + fw.w*E3.y;
        f[2] = fw.x*E0.z + fw.y*E1.z + fw.z*E2v.z + fw.w*E3.z;
        f[3] = fw.x*E0.w + fw.y*E1.w + fw.z*E2v.w + fw.w*E3.w;
        const size_t base = (size_t)(b*Cc + o)*HWn + p0;
        const uint2 xu = *(const uint2*)(xbf + base);
        float xa[4];
        xa[0] = bf2f((u16)(xu.x & 0xffff)); xa[1] = bf2f((u16)(xu.x >> 16));
        xa[2] = bf2f((u16)(xu.y & 0xffff)); xa[3] = bf2f((u16)(xu.y >> 16));
        float4 r; float* rp = &r.x;
        #pragma unroll
        for (int j = 0; j < 4; ++j) {
            float z = al*f[j] + be;
            z = fmaxf(z, 0.f);
            rp[j] = xa[j] / (1.f + __expf(-z));
        }
        *(float4*)(out + base) = r;
    }
}

extern "C" void kernel_launch(void* const* d_in, const int* in_sizes, int n_in,
                              void* d_out, int out_size, void* d_ws, size_t ws_size,
                              hipStream_t stream)
{
    const float* x   = (const float*)d_in[0];
    const float* qw  = (const float*)d_in[1];
    const float* kw  = (const float*)d_in[2];
    const float* r_q = (const float*)d_in[3];
    const float* rk0 = (const float*)d_in[4];
    const float* rk1 = (const float*)d_in[5];
    const float* rk2 = (const float*)d_in[6];
    const float* rk3 = (const float*)d_in[7];
    const float* fw  = (const float*)d_in[8];
    const float* gm  = (const float*)d_in[9];
    const float* bt  = (const float*)d_in[10];
    float* out = (float*)d_out;
    float* ws  = (float*)d_ws;

    u16*   t     = (u16*)(ws + T_OFF);          // bf16 t, 33.5 MB
    u16*   xbf   = (u16*)ws + 16777216;         // bf16 x copy, second half of T region
    float* ebuf  = ws + E_OFF;                  // combined e (f32), 1 MB
    float* stats = ws + ST_OFF;
    u16*   Abf   = (u16*)(ws + A_OFF);          // fragment-packed bf16 A
    float* cvec  = ws + CV_OFF;
    float* fwr   = ws + FW_OFF;
    u16*   eh    = (u16*)out;                   // 4 MB bf16 partial planes staged in d_out

    k0_precompute<<<5,    256, 0, stream>>>(qw, kw, rk0, rk1, rk2, rk3, fw, Abf, cvec, fwr, stats);
    k1_mfma      <<<1024, 256, 0, stream>>>(x, Abf, t, xbf);
    k23_fused    <<<1024, 256, 0, stream>>>(t, xbf, r_q, cvec, eh);
    k3b_stats    <<<256,  256, 0, stream>>>(eh, ebuf, stats);
    k5_out       <<<2048, 256, 0, stream>>>(xbf, ebuf, fwr, stats, gm, bt, out);
}

// Round 14
// 89.533 us; speedup vs baseline: 1.0010x; 1.0010x over previous
//
#include <hip/hip_runtime.h>

#define Bb 4
#define Cc 256
#define GC_ 64
#define Hh 128
#define Wd 128
#define HWn 16384
#define NPIX 65536
#define EPS 1e-5f

// workspace layout (float offsets). T region holds t (bf16) then xbf (bf16).
#define T_OFF   0
#define E_OFF   16777216
#define ST_OFF  (E_OFF + NPIX*4)
#define A_OFF   (ST_OFF + 16)      // Abf: 16384 u16 = 32KB, fragment-packed
#define CV_OFF  (A_OFF + 16384)
#define FW_OFF  (CV_OFF + 256)

typedef __attribute__((ext_vector_type(8))) short short8v;
typedef __attribute__((ext_vector_type(4))) float f32x4;
typedef unsigned short u16;

__device__ inline u16 f2bf(float f) {
    union { float f; unsigned u; } v; v.f = f;
    unsigned r = v.u + 0x7fff + ((v.u >> 16) & 1);   // RNE
    return (u16)(r >> 16);
}
__device__ inline float bf2f(u16 u) {
    union { unsigned u; float f; } v; v.u = ((unsigned)u) << 16;
    return v.f;
}

// K0: Abf_g = bf16(qw_g^T @ kw_g) fragment-packed; cvec; fwred; zero stats.
__global__ __launch_bounds__(256) void k0_precompute(
    const float* __restrict__ qw, const float* __restrict__ kw,
    const float* __restrict__ rk0, const float* __restrict__ rk1,
    const float* __restrict__ rk2, const float* __restrict__ rk3,
    const float* __restrict__ fusion_w,
    u16* __restrict__ Abf, float* __restrict__ cvec, float* __restrict__ fwred,
    float* __restrict__ stats)
{
    const int tid = threadIdx.x;
    if (blockIdx.x == 4) {
        if (tid < 16) stats[tid] = 0.f;
        for (int i = 0; i < 4; ++i) {
            float s = 0.f;
            const float* fp = fusion_w + tid*256 + i*64;
            #pragma unroll 8
            for (int c = 0; c < 64; ++c) s += fp[c];
            fwred[tid*4 + i] = s;
        }
        return;
    }
    const int g = blockIdx.x;
    __shared__ float qwL[4096];
    __shared__ float kwL[4096];
    __shared__ float rks[64];
    for (int i = tid; i < 4096; i += 256) {
        qwL[i] = qw[g*4096 + i];
        kwL[i] = kw[g*4096 + i];
    }
    __syncthreads();
    if (tid < 64) {
        const float* rkp = (g==0)?rk0:(g==1)?rk1:(g==2)?rk2:rk3;
        const int R = 4*g + 9;               // 2L-1 for L={5,7,9,11}
        float s = 0.f;
        for (int r = 0; r < R; ++r) s += rkp[tid*R + r];
        rks[tid] = s;
    }
    __syncthreads();
    for (int idx = tid; idx < 4096; idx += 256) {
        const int ct = idx >> 10, kh = (idx >> 9) & 1;
        const int lane = (idx >> 3) & 63, j = idx & 7;
        const int c = ct*16 + (lane & 15);
        const int d = kh*32 + (lane >> 4)*8 + j;
        float s = 0.f;
        #pragma unroll
        for (int o = 0; o < 64; ++o) s += qwL[o*64 + c] * kwL[o*64 + d];
        Abf[g*4096 + idx] = f2bf(s);
    }
    if (tid < 64) {
        float s = 0.f;
        #pragma unroll
        for (int o = 0; o < 64; ++o) s += qwL[o*64 + tid] * rks[o];
        cvec[g*64 + tid] = s;
    }
}

// K1 (MFMA, R12 version — proven best): t = A_g x (bf16), xbf = bf16(x).
// x read once (coalesced float4) -> LDS [64ch][132] + xbf; A-frags 8x16B prepacked.
__global__ __launch_bounds__(256) void k1_mfma(
    const float* __restrict__ x, const u16* __restrict__ Abf,
    u16* __restrict__ t, u16* __restrict__ xbf)
{
    __shared__ u16 xt[64*132];
    const int tid = threadIdx.x;
    const int wv = tid >> 6, lane = tid & 63;
    const int chunk = blockIdx.x & 127;
    const int g = (blockIdx.x >> 7) & 3;
    const int b = blockIdx.x >> 9;
    const int l15 = lane & 15, lg = lane >> 4;
    const int px0 = chunk*128;

    const u16* Ab = Abf + g*4096;
    short8v afr[4][2];
    #pragma unroll
    for (int ct = 0; ct < 4; ++ct)
      #pragma unroll
      for (int kh = 0; kh < 2; ++kh)
        afr[ct][kh] = *(const short8v*)(Ab + ((ct*2 + kh)*64 + lane)*8);

    const float* xg = x   + (size_t)(b*Cc + g*GC_)*HWn;
    u16* tg        = t    + (size_t)(b*Cc + g*GC_)*HWn;
    u16* xbg       = xbf  + (size_t)(b*Cc + g*GC_)*HWn;

    #pragma unroll
    for (int i = 0; i < 8; ++i) {
        const int idx = tid + i*256;
        const int ch = idx >> 5, q = (idx & 31) << 2;
        const float4 v = *(const float4*)(xg + (size_t)ch*HWn + px0 + q);
        u16 o4[4] __attribute__((aligned(8))) = {f2bf(v.x), f2bf(v.y), f2bf(v.z), f2bf(v.w)};
        *(uint2*)(xt + ch*132 + q) = *(const uint2*)o4;
        *(uint2*)(xbg + (size_t)ch*HWn + px0 + q) = *(const uint2*)o4;
    }
    __syncthreads();

    const int pw = wv*32;
    #pragma unroll
    for (int nt = 0; nt < 2; ++nt) {
        const int pt = pw + nt*16 + l15;
        short8v bfr[2];
        #pragma unroll
        for (int kh = 0; kh < 2; ++kh)
          #pragma unroll
          for (int j = 0; j < 8; ++j)
            bfr[kh][j] = (short)xt[(kh*32 + lg*8 + j)*132 + pt];
        #pragma unroll
        for (int ct = 0; ct < 4; ++ct) {
            f32x4 acc = {0.f, 0.f, 0.f, 0.f};
            acc = __builtin_amdgcn_mfma_f32_16x16x32_bf16(bfr[0], afr[ct][0], acc, 0, 0, 0);
            acc = __builtin_amdgcn_mfma_f32_16x16x32_bf16(bfr[1], afr[ct][1], acc, 0, 0, 0);
            u16 ov[4] __attribute__((aligned(8)));
            #pragma unroll
            for (int r = 0; r < 4; ++r) ov[r] = f2bf(acc[r]);
            *(uint2*)(tg + (size_t)(ct*16 + l15)*HWn + px0 + pw + nt*16 + lg*4) = *(const uint2*)ov;
        }
    }
}

// K23 v5: fused cross-sum + e accumulation; 8 channels/block (grid 2048 -> 6 blocks/CU
// resident, R11's proven occupancy) + bf16 eh (R12's proven traffic cut), 16 planes.
__global__ __launch_bounds__(256) void k23_fused(
    const u16* __restrict__ t, const u16* __restrict__ xbf,
    const float* __restrict__ r_q, const float* __restrict__ cvec,
    u16* __restrict__ eh)
{
    __shared__ u16 timg[4][18*132];     // 2 live + 2 prefetch-dest; fixed 18 rows staged
    __shared__ u16 simg[2][8*132];
    __shared__ float rqL[8], cvL[8];
    const int tid = threadIdx.x;
    const int bid = blockIdx.x;
    const int wk = (bid & 7)*256 + (bid >> 3);   // 2048 = 8*256, bijective
    const int quarter = wk & 7;          // 8 channels
    const int htile = (wk >> 3) & 15;    // 8 rows
    const int g = (wk >> 7) & 3;
    const int b = wk >> 9;
    const int p = g + 2;                 // pad {2,3,4,5}
    const int h0 = htile*8;
    const int c0 = quarter*8;

    if (tid < 8) { rqL[tid] = r_q[g*64 + c0 + tid]; cvL[tid] = cvec[g*64 + c0 + tid]; }

    const u16* tbase = t   + (size_t)(b*Cc + g*GC_ + c0)*HWn;
    const u16* xbase = xbf + (size_t)(b*Cc + g*GC_ + c0)*HWn;

    // stage pair 0: fixed 18 rows per channel (zero-fill OOB; extra rows unused)
    #pragma unroll
    for (int k = 0; k < 3; ++k) {
        const int idx = tid + k*256;
        if (idx < 576) {
            const int r = idx >> 5, w4 = (idx & 31) << 2;
            const int hh = h0 - p + r;
            uint2 v0 = make_uint2(0u,0u), v1 = make_uint2(0u,0u);
            if (hh >= 0 && hh < 128) {
                v0 = *(const uint2*)(tbase + (hh<<7) + w4);
                v1 = *(const uint2*)(tbase + HWn + (hh<<7) + w4);
            }
            *(uint2*)(&timg[0][r*132 + w4]) = v0;
            *(uint2*)(&timg[1][r*132 + w4]) = v1;
        }
    }
    __syncthreads();

    // fixed per-thread mappings
    const int vch = tid >> 7, vcol = tid & 127;                      // vertical
    const int hch = tid >> 7, hr = (tid & 127) >> 4, hseg = tid & 15, hw0 = hseg*8; // horizontal
    float er[8];
    #pragma unroll
    for (int j = 0; j < 8; ++j) er[j] = 0.f;

    for (int it = 0; it < 4; ++it) {
        const int curp = (it & 1)*2;
        // prefetch next pair into regs (static indices)
        uint2 pr0[3], pr1[3];
        if (it < 3) {
            const u16* tn0 = tbase + (size_t)(2*it + 2)*HWn;
            const u16* tn1 = tn0 + HWn;
            #pragma unroll
            for (int k = 0; k < 3; ++k) {
                const int idx = tid + k*256;
                pr0[k] = make_uint2(0u,0u); pr1[k] = make_uint2(0u,0u);
                if (idx < 576) {
                    const int r = idx >> 5, w4 = (idx & 31) << 2;
                    const int hh = h0 - p + r;
                    if (hh >= 0 && hh < 128) {
                        pr0[k] = *(const uint2*)(tn0 + (hh<<7) + w4);
                        pr1[k] = *(const uint2*)(tn1 + (hh<<7) + w4);
                    }
                }
            }
        }

        // vertical sliding box: this half's channel, 1 col x 8 rows
        {
            const u16* tb = &timg[curp + vch][0];
            float run = 0.f;
            for (int j = 0; j <= 2*p; ++j) run += bf2f(tb[j*132 + vcol]);
            #pragma unroll
            for (int i = 0; i < 8; ++i) {
                simg[vch][i*132 + vcol] = f2bf(run);
                if (i != 7)
                    run += bf2f(tb[(i + 1 + 2*p)*132 + vcol]) - bf2f(tb[i*132 + vcol]);
            }
        }
        __syncthreads();

        // horizontal sliding + combine + accumulate: 1 row x 8 px per thread
        {
            const int cc = it*2 + hch;
            const u16* trow = &timg[curp + hch][(hr + p)*132];
            float run = 0.f;
            const int lo = max(hw0 - p, 0), hi = min(hw0 + p, 127);
            for (int ww = lo; ww <= hi; ++ww) run += bf2f(trow[ww]);
            const float rq = rqL[cc], cv = cvL[cc];
            union { uint4 q; u16 s[8]; } xu;
            xu.q = *(const uint4*)(xbase + (size_t)cc*HWn + ((h0 + hr) << 7) + hw0);
            #pragma unroll
            for (int j = 0; j < 8; ++j) {
                const int w = hw0 + j;
                const float S = run + bf2f(simg[hch][hr*132 + w]) - bf2f(trow[w]);
                er[j] += (bf2f(xu.s[j]) + rq) * (S + cv);
                run += (w + 1 + p < 128 ? bf2f(trow[w + 1 + p]) : 0.f)
                     - (w - p     >= 0  ? bf2f(trow[w - p])     : 0.f);
            }
        }
        // write prefetched pair into the other buffers
        if (it < 3) {
            const int nxt = curp ^ 2;
            #pragma unroll
            for (int k = 0; k < 3; ++k) {
                const int idx = tid + k*256;
                if (idx < 576) {
                    const int r = idx >> 5, w4 = (idx & 31) << 2;
                    *(uint2*)(&timg[nxt + 0][r*132 + w4]) = pr0[k];
                    *(uint2*)(&timg[nxt + 1][r*132 + w4]) = pr1[k];
                }
            }
        }
        __syncthreads();
    }

    // write partial e plane (quarter*2 + hch) as bf16 (8 u16 = one uint4)
    u16 ov[8] __attribute__((aligned(16)));
    #pragma unroll
    for (int j = 0; j < 8; ++j) ov[j] = f2bf(er[j]);
    u16* ep = eh + (size_t)((quarter*2 + hch)*16 + b*4 + g)*HWn + ((h0 + hr) << 7) + hw0;
    *(uint4*)ep = *(const uint4*)ov;
}

// K3b: combine 16 bf16 partial planes -> ebuf (f32); 4x4 moment matrix (14 scalars).
__global__ __launch_bounds__(256) void k3b_stats(
    const u16* __restrict__ eh, float* __restrict__ ebuf, float* __restrict__ stats)
{
    __shared__ float red[4*14];
    const int tid = threadIdx.x;
    const int q = blockIdx.x*256 + tid;
    const int b = q >> 14, p = q & (HWn - 1);
    float e4[4];
    #pragma unroll
    for (int g = 0; g < 4; ++g) {
        float s = 0.f;
        #pragma unroll
        for (int qq = 0; qq < 16; ++qq)
            s += bf2f(eh[(size_t)(qq*16 + b*4 + g)*HWn + p]);
        e4[g] = s;
        ebuf[(size_t)(b*4 + g)*HWn + p] = s;
    }
    const float e0 = e4[0], e1 = e4[1], e2 = e4[2], e3 = e4[3];
    float v[14];
    v[0]=e0; v[1]=e1; v[2]=e2; v[3]=e3;
    v[4]=e0*e0; v[5]=e0*e1; v[6]=e0*e2; v[7]=e0*e3;
    v[8]=e1*e1; v[9]=e1*e2; v[10]=e1*e3;
    v[11]=e2*e2; v[12]=e2*e3; v[13]=e3*e3;
    #pragma unroll
    for (int kk = 0; kk < 14; ++kk) {
        float s = v[kk];
        for (int off = 32; off > 0; off >>= 1) s += __shfl_down(s, off, 64);
        v[kk] = s;
    }
    const int lane = tid & 63, wv = tid >> 6;
    if (lane == 0) {
        #pragma unroll
        for (int kk = 0; kk < 14; ++kk) red[wv*14 + kk] = v[kk];
    }
    __syncthreads();
    if (tid < 14) atomicAdd(&stats[tid], red[tid] + red[14+tid] + red[28+tid] + red[42+tid]);
}

// K5: out = x * sigmoid(relu(alpha*(fwred·e)+beta2)); 8 channels/block; BN-fold inline.
__global__ __launch_bounds__(256) void k5_out(
    const u16* __restrict__ xbf, const float* __restrict__ ebuf,
    const float* __restrict__ fwred, const float* __restrict__ stats,
    const float* __restrict__ gamma, const float* __restrict__ beta,
    float* __restrict__ out)
{
    const int tid = threadIdx.x;
    const int chunk = blockIdx.x & 15;
    const int oct = (blockIdx.x >> 4) & 31;
    const int b = blockIdx.x >> 9;
    __shared__ float alL[8], beL[8];
    __shared__ float4 fwL[8];
    if (tid < 8) {
        const int o = oct*8 + tid;
        const float invN = 1.f / (float)NPIX;
        const float me0 = stats[0]*invN, me1 = stats[1]*invN, me2 = stats[2]*invN, me3 = stats[3]*invN;
        const float m00 = stats[4]*invN,  m01 = stats[5]*invN,  m02 = stats[6]*invN,  m03 = stats[7]*invN;
        const float m11 = stats[8]*invN,  m12 = stats[9]*invN,  m13 = stats[10]*invN;
        const float m22 = stats[11]*invN, m23 = stats[12]*invN, m33 = stats[13]*invN;
        const float4 fw = ((const float4*)fwred)[o];
        const float Ef = fw.x*me0 + fw.y*me1 + fw.z*me2 + fw.w*me3;
        const float E2 = fw.x*fw.x*m00 + fw.y*fw.y*m11 + fw.z*fw.z*m22 + fw.w*fw.w*m33
                       + 2.f*(fw.x*fw.y*m01 + fw.x*fw.z*m02 + fw.x*fw.w*m03
                            + fw.y*fw.z*m12 + fw.y*fw.w*m13 + fw.z*fw.w*m23);
        const float a = gamma[o] * rsqrtf(E2 - Ef*Ef + EPS);
        alL[tid] = a;
        beL[tid] = beta[o] - Ef*a;
        fwL[tid] = fw;
    }
    __syncthreads();

    const int p0 = chunk*1024 + tid*4;
    const float* eb = ebuf + (size_t)b*4*HWn;
    const float4 E0 = *(const float4*)(eb + 0*HWn + p0);
    const float4 E1 = *(const float4*)(eb + 1*HWn + p0);
    const float4 E2v = *(const float4*)(eb + 2*HWn + p0);
    const float4 E3 = *(const float4*)(eb + 3*HWn + p0);

    #pragma unroll
    for (int c = 0; c < 8; ++c) {
        const int o = oct*8 + c;
        const float4 fw = fwL[c];
        const float al = alL[c], be = beL[c];
        float f[4];
        f[0] = fw.x*E0.x + fw.y*E1.x + fw.z*E2v.x + fw.w*E3.x;
        f[1] = fw.x*E0.y + fw.y*E1.y + fw.z*E2v.y + fw.w*E3.y;
        f[2] = fw.x*E0.z + fw.y*E1.z + fw.z*E2v.z + fw.w*E3.z;
        f[3] = fw.x*E0.w + fw.y*E1.w + fw.z*E2v.w + fw.w*E3.w;
        const size_t base = (size_t)(b*Cc + o)*HWn + p0;
        const uint2 xu = *(const uint2*)(xbf + base);
        float xa[4];
        xa[0] = bf2f((u16)(xu.x & 0xffff)); xa[1] = bf2f((u16)(xu.x >> 16));
        xa[2] = bf2f((u16)(xu.y & 0xffff)); xa[3] = bf2f((u16)(xu.y >> 16));
        float4 r; float* rp = &r.x;
        #pragma unroll
        for (int j = 0; j < 4; ++j) {
            float z = al*f[j] + be;
            z = fmaxf(z, 0.f);
            rp[j] = xa[j] / (1.f + __expf(-z));
        }
        *(float4*)(out + base) = r;
    }
}

extern "C" void kernel_launch(void* const* d_in, const int* in_sizes, int n_in,
                              void* d_out, int out_size, void* d_ws, size_t ws_size,
                              hipStream_t stream)
{
    const float* x   = (const float*)d_in[0];
    const float* qw  = (const float*)d_in[1];
    const float* kw  = (const float*)d_in[2];
    const float* r_q = (const float*)d_in[3];
    const float* rk0 = (const float*)d_in[4];
    const float* rk1 = (const float*)d_in[5];
    const float* rk2 = (const float*)d_in[6];
    const float* rk3 = (const float*)d_in[7];
    const float* fw  = (const float*)d_in[8];
    const float* gm  = (const float*)d_in[9];
    const float* bt  = (const float*)d_in[10];
    float* out = (float*)d_out;
    float* ws  = (float*)d_ws;

    u16*   t     = (u16*)(ws + T_OFF);          // bf16 t, 33.5 MB
    u16*   xbf   = (u16*)ws + 16777216;         // bf16 x copy, second half of T region
    float* ebuf  = ws + E_OFF;                  // combined e (f32), 1 MB
    float* stats = ws + ST_OFF;
    u16*   Abf   = (u16*)(ws + A_OFF);          // fragment-packed bf16 A
    float* cvec  = ws + CV_OFF;
    float* fwr   = ws + FW_OFF;
    u16*   eh    = (u16*)out;                   // 8 MB bf16 partial planes staged in d_out

    k0_precompute<<<5,    256, 0, stream>>>(qw, kw, rk0, rk1, rk2, rk3, fw, Abf, cvec, fwr, stats);
    k1_mfma      <<<2048, 256, 0, stream>>>(x, Abf, t, xbf);
    k23_fused    <<<2048, 256, 0, stream>>>(t, xbf, r_q, cvec, eh);
    k3b_stats    <<<256,  256, 0, stream>>>(eh, ebuf, stats);
    k5_out       <<<2048, 256, 0, stream>>>(xbf, ebuf, fwr, stats, gm, bt, out);
}

// Round 15
// 88.589 us; speedup vs baseline: 1.0117x; 1.0107x over previous
//
#include <hip/hip_runtime.h>

#define Bb 4
#define Cc 256
#define GC_ 64
#define Hh 128
#define Wd 128
#define HWn 16384
#define NPIX 65536
#define EPS 1e-5f

// workspace layout (float offsets). T region holds t (bf16) then xbf (bf16).
#define T_OFF   0
#define E_OFF   16777216
#define ST_OFF  (E_OFF + NPIX*4)
#define A_OFF   (ST_OFF + 16)      // Abf: 16384 u16 = 32KB, fragment-packed
#define CV_OFF  (A_OFF + 16384)
#define FW_OFF  (CV_OFF + 256)

typedef __attribute__((ext_vector_type(8))) short short8v;
typedef __attribute__((ext_vector_type(4))) float f32x4;
typedef unsigned short u16;

__device__ inline u16 f2bf(float f) {
    union { float f; unsigned u; } v; v.f = f;
    unsigned r = v.u + 0x7fff + ((v.u >> 16) & 1);   // RNE
    return (u16)(r >> 16);
}
__device__ inline float bf2f(u16 u) {
    union { unsigned u; float f; } v; v.u = ((unsigned)u) << 16;
    return v.f;
}

// K0: Abf_g = bf16(qw_g^T @ kw_g) fragment-packed; cvec; fwred; zero stats.
__global__ __launch_bounds__(256) void k0_precompute(
    const float* __restrict__ qw, const float* __restrict__ kw,
    const float* __restrict__ rk0, const float* __restrict__ rk1,
    const float* __restrict__ rk2, const float* __restrict__ rk3,
    const float* __restrict__ fusion_w,
    u16* __restrict__ Abf, float* __restrict__ cvec, float* __restrict__ fwred,
    float* __restrict__ stats)
{
    const int tid = threadIdx.x;
    if (blockIdx.x == 4) {
        if (tid < 16) stats[tid] = 0.f;
        for (int i = 0; i < 4; ++i) {
            float s = 0.f;
            const float* fp = fusion_w + tid*256 + i*64;
            #pragma unroll 8
            for (int c = 0; c < 64; ++c) s += fp[c];
            fwred[tid*4 + i] = s;
        }
        return;
    }
    const int g = blockIdx.x;
    __shared__ float qwL[4096];
    __shared__ float kwL[4096];
    __shared__ float rks[64];
    for (int i = tid; i < 4096; i += 256) {
        qwL[i] = qw[g*4096 + i];
        kwL[i] = kw[g*4096 + i];
    }
    __syncthreads();
    if (tid < 64) {
        const float* rkp = (g==0)?rk0:(g==1)?rk1:(g==2)?rk2:rk3;
        const int R = 4*g + 9;               // 2L-1 for L={5,7,9,11}
        float s = 0.f;
        for (int r = 0; r < R; ++r) s += rkp[tid*R + r];
        rks[tid] = s;
    }
    __syncthreads();
    for (int idx = tid; idx < 4096; idx += 256) {
        const int ct = idx >> 10, kh = (idx >> 9) & 1;
        const int lane = (idx >> 3) & 63, j = idx & 7;
        const int c = ct*16 + (lane & 15);
        const int d = kh*32 + (lane >> 4)*8 + j;
        float s = 0.f;
        #pragma unroll
        for (int o = 0; o < 64; ++o) s += qwL[o*64 + c] * kwL[o*64 + d];
        Abf[g*4096 + idx] = f2bf(s);
    }
    if (tid < 64) {
        float s = 0.f;
        #pragma unroll
        for (int o = 0; o < 64; ++o) s += qwL[o*64 + tid] * rks[o];
        cvec[g*64 + tid] = s;
    }
}

// K1 (MFMA): t = A_g x (bf16), xbf = bf16(x). R12 proven-best version.
__global__ __launch_bounds__(256) void k1_mfma(
    const float* __restrict__ x, const u16* __restrict__ Abf,
    u16* __restrict__ t, u16* __restrict__ xbf)
{
    __shared__ u16 xt[64*132];
    const int tid = threadIdx.x;
    const int wv = tid >> 6, lane = tid & 63;
    const int chunk = blockIdx.x & 127;
    const int g = (blockIdx.x >> 7) & 3;
    const int b = blockIdx.x >> 9;
    const int l15 = lane & 15, lg = lane >> 4;
    const int px0 = chunk*128;

    const u16* Ab = Abf + g*4096;
    short8v afr[4][2];
    #pragma unroll
    for (int ct = 0; ct < 4; ++ct)
      #pragma unroll
      for (int kh = 0; kh < 2; ++kh)
        afr[ct][kh] = *(const short8v*)(Ab + ((ct*2 + kh)*64 + lane)*8);

    const float* xg = x   + (size_t)(b*Cc + g*GC_)*HWn;
    u16* tg        = t    + (size_t)(b*Cc + g*GC_)*HWn;
    u16* xbg       = xbf  + (size_t)(b*Cc + g*GC_)*HWn;

    #pragma unroll
    for (int i = 0; i < 8; ++i) {
        const int idx = tid + i*256;
        const int ch = idx >> 5, q = (idx & 31) << 2;
        const float4 v = *(const float4*)(xg + (size_t)ch*HWn + px0 + q);
        u16 o4[4] __attribute__((aligned(8))) = {f2bf(v.x), f2bf(v.y), f2bf(v.z), f2bf(v.w)};
        *(uint2*)(xt + ch*132 + q) = *(const uint2*)o4;
        *(uint2*)(xbg + (size_t)ch*HWn + px0 + q) = *(const uint2*)o4;
    }
    __syncthreads();

    const int pw = wv*32;
    #pragma unroll
    for (int nt = 0; nt < 2; ++nt) {
        const int pt = pw + nt*16 + l15;
        short8v bfr[2];
        #pragma unroll
        for (int kh = 0; kh < 2; ++kh)
          #pragma unroll
          for (int j = 0; j < 8; ++j)
            bfr[kh][j] = (short)xt[(kh*32 + lg*8 + j)*132 + pt];
        #pragma unroll
        for (int ct = 0; ct < 4; ++ct) {
            f32x4 acc = {0.f, 0.f, 0.f, 0.f};
            acc = __builtin_amdgcn_mfma_f32_16x16x32_bf16(bfr[0], afr[ct][0], acc, 0, 0, 0);
            acc = __builtin_amdgcn_mfma_f32_16x16x32_bf16(bfr[1], afr[ct][1], acc, 0, 0, 0);
            u16 ov[4] __attribute__((aligned(8)));
            #pragma unroll
            for (int r = 0; r < 4; ++r) ov[r] = f2bf(acc[r]);
            *(uint2*)(tg + (size_t)(ct*16 + l15)*HWn + px0 + pw + nt*16 + lg*4) = *(const uint2*)ov;
        }
    }
}

// K23 v4 (R12 proven-best): fused cross-sum + e accumulation; 16 channels/block,
// 8-row tiles, grid 1024. Partial e planes stored bf16 (8 planes).
__global__ __launch_bounds__(256) void k23_fused(
    const u16* __restrict__ t, const u16* __restrict__ xbf,
    const float* __restrict__ r_q, const float* __restrict__ cvec,
    u16* __restrict__ eh)
{
    __shared__ u16 timg[4][18*132];     // 2 live + 2 prefetch-dest; fixed 18 rows staged
    __shared__ u16 simg[2][8*132];
    __shared__ float rqL[16], cvL[16];
    const int tid = threadIdx.x;
    const int bid = blockIdx.x;
    const int wk = (bid & 7)*128 + (bid >> 3);   // 1024 = 8*128, bijective
    const int qh = wk & 3;               // 16-channel group
    const int htile = (wk >> 2) & 15;    // 8 rows
    const int g = (wk >> 6) & 3;
    const int b = wk >> 8;
    const int p = g + 2;                 // pad {2,3,4,5}
    const int h0 = htile*8;
    const int c0 = qh*16;

    if (tid < 16) { rqL[tid] = r_q[g*64 + c0 + tid]; cvL[tid] = cvec[g*64 + c0 + tid]; }

    const u16* tbase = t   + (size_t)(b*Cc + g*GC_ + c0)*HWn;
    const u16* xbase = xbf + (size_t)(b*Cc + g*GC_ + c0)*HWn;

    // stage pair 0: fixed 18 rows per channel (zero-fill OOB; extra rows unused)
    #pragma unroll
    for (int k = 0; k < 3; ++k) {
        const int idx = tid + k*256;
        if (idx < 576) {
            const int r = idx >> 5, w4 = (idx & 31) << 2;
            const int hh = h0 - p + r;
            uint2 v0 = make_uint2(0u,0u), v1 = make_uint2(0u,0u);
            if (hh >= 0 && hh < 128) {
                v0 = *(const uint2*)(tbase + (hh<<7) + w4);
                v1 = *(const uint2*)(tbase + HWn + (hh<<7) + w4);
            }
            *(uint2*)(&timg[0][r*132 + w4]) = v0;
            *(uint2*)(&timg[1][r*132 + w4]) = v1;
        }
    }
    __syncthreads();

    // fixed per-thread mappings
    const int vch = tid >> 7, vcol = tid & 127;                      // vertical
    const int hch = tid >> 7, hr = (tid & 127) >> 4, hseg = tid & 15, hw0 = hseg*8; // horizontal
    float er[8];
    #pragma unroll
    for (int j = 0; j < 8; ++j) er[j] = 0.f;

    for (int it = 0; it < 8; ++it) {
        const int curp = (it & 1)*2;
        // prefetch next pair into regs (static indices)
        uint2 pr0[3], pr1[3];
        if (it < 7) {
            const u16* tn0 = tbase + (size_t)(2*it + 2)*HWn;
            const u16* tn1 = tn0 + HWn;
            #pragma unroll
            for (int k = 0; k < 3; ++k) {
                const int idx = tid + k*256;
                pr0[k] = make_uint2(0u,0u); pr1[k] = make_uint2(0u,0u);
                if (idx < 576) {
                    const int r = idx >> 5, w4 = (idx & 31) << 2;
                    const int hh = h0 - p + r;
                    if (hh >= 0 && hh < 128) {
                        pr0[k] = *(const uint2*)(tn0 + (hh<<7) + w4);
                        pr1[k] = *(const uint2*)(tn1 + (hh<<7) + w4);
                    }
                }
            }
        }

        // vertical sliding box: this half's channel, 1 col x 8 rows
        {
            const u16* tb = &timg[curp + vch][0];
            float run = 0.f;
            for (int j = 0; j <= 2*p; ++j) run += bf2f(tb[j*132 + vcol]);
            #pragma unroll
            for (int i = 0; i < 8; ++i) {
                simg[vch][i*132 + vcol] = f2bf(run);
                if (i != 7)
                    run += bf2f(tb[(i + 1 + 2*p)*132 + vcol]) - bf2f(tb[i*132 + vcol]);
            }
        }
        __syncthreads();

        // horizontal sliding + combine + accumulate: 1 row x 8 px per thread
        {
            const int cc = it*2 + hch;
            const u16* trow = &timg[curp + hch][(hr + p)*132];
            float run = 0.f;
            const int lo = max(hw0 - p, 0), hi = min(hw0 + p, 127);
            for (int ww = lo; ww <= hi; ++ww) run += bf2f(trow[ww]);
            const float rq = rqL[cc], cv = cvL[cc];
            union { uint4 q; u16 s[8]; } xu;
            xu.q = *(const uint4*)(xbase + (size_t)cc*HWn + ((h0 + hr) << 7) + hw0);
            #pragma unroll
            for (int j = 0; j < 8; ++j) {
                const int w = hw0 + j;
                const float S = run + bf2f(simg[hch][hr*132 + w]) - bf2f(trow[w]);
                er[j] += (bf2f(xu.s[j]) + rq) * (S + cv);
                run += (w + 1 + p < 128 ? bf2f(trow[w + 1 + p]) : 0.f)
                     - (w - p     >= 0  ? bf2f(trow[w - p])     : 0.f);
            }
        }
        // write prefetched pair into the other buffers
        if (it < 7) {
            const int nxt = curp ^ 2;
            #pragma unroll
            for (int k = 0; k < 3; ++k) {
                const int idx = tid + k*256;
                if (idx < 576) {
                    const int r = idx >> 5, w4 = (idx & 31) << 2;
                    *(uint2*)(&timg[nxt + 0][r*132 + w4]) = pr0[k];
                    *(uint2*)(&timg[nxt + 1][r*132 + w4]) = pr1[k];
                }
            }
        }
        __syncthreads();
    }

    // write partial e plane (qh*2 + hch) as bf16 (8 u16 = one uint4)
    u16 ov[8] __attribute__((aligned(16)));
    #pragma unroll
    for (int j = 0; j < 8; ++j) ov[j] = f2bf(er[j]);
    u16* ep = eh + (size_t)((qh*2 + hch)*16 + b*4 + g)*HWn + ((h0 + hr) << 7) + hw0;
    *(uint4*)ep = *(const uint4*)ov;
}

// K3b: combine 8 bf16 partial planes -> ebuf (f32); 4x4 moment matrix (14 scalars).
__global__ __launch_bounds__(256) void k3b_stats(
    const u16* __restrict__ eh, float* __restrict__ ebuf, float* __restrict__ stats)
{
    __shared__ float red[4*14];
    const int tid = threadIdx.x;
    const int q = blockIdx.x*256 + tid;
    const int b = q >> 14, p = q & (HWn - 1);
    float e4[4];
    #pragma unroll
    for (int g = 0; g < 4; ++g) {
        float s = 0.f;
        #pragma unroll
        for (int qq = 0; qq < 8; ++qq)
            s += bf2f(eh[(size_t)(qq*16 + b*4 + g)*HWn + p]);
        e4[g] = s;
        ebuf[(size_t)(b*4 + g)*HWn + p] = s;
    }
    const float e0 = e4[0], e1 = e4[1], e2 = e4[2], e3 = e4[3];
    float v[14];
    v[0]=e0; v[1]=e1; v[2]=e2; v[3]=e3;
    v[4]=e0*e0; v[5]=e0*e1; v[6]=e0*e2; v[7]=e0*e3;
    v[8]=e1*e1; v[9]=e1*e2; v[10]=e1*e3;
    v[11]=e2*e2; v[12]=e2*e3; v[13]=e3*e3;
    #pragma unroll
    for (int kk = 0; kk < 14; ++kk) {
        float s = v[kk];
        for (int off = 32; off > 0; off >>= 1) s += __shfl_down(s, off, 64);
        v[kk] = s;
    }
    const int lane = tid & 63, wv = tid >> 6;
    if (lane == 0) {
        #pragma unroll
        for (int kk = 0; kk < 14; ++kk) red[wv*14 + kk] = v[kk];
    }
    __syncthreads();
    if (tid < 14) atomicAdd(&stats[tid], red[tid] + red[14+tid] + red[28+tid] + red[42+tid]);
}

// K5: out = x * sigmoid(relu(alpha*(fwred·e)+beta2)); 8 channels/block; BN-fold inline.
__global__ __launch_bounds__(256) void k5_out(
    const u16* __restrict__ xbf, const float* __restrict__ ebuf,
    const float* __restrict__ fwred, const float* __restrict__ stats,
    const float* __restrict__ gamma, const float* __restrict__ beta,
    float* __restrict__ out)
{
    const int tid = threadIdx.x;
    const int chunk = blockIdx.x & 15;
    const int oct = (blockIdx.x >> 4) & 31;
    const int b = blockIdx.x >> 9;
    __shared__ float alL[8], beL[8];
    __shared__ float4 fwL[8];
    if (tid < 8) {
        const int o = oct*8 + tid;
        const float invN = 1.f / (float)NPIX;
        const float me0 = stats[0]*invN, me1 = stats[1]*invN, me2 = stats[2]*invN, me3 = stats[3]*invN;
        const float m00 = stats[4]*invN,  m01 = stats[5]*invN,  m02 = stats[6]*invN,  m03 = stats[7]*invN;
        const float m11 = stats[8]*invN,  m12 = stats[9]*invN,  m13 = stats[10]*invN;
        const float m22 = stats[11]*invN, m23 = stats[12]*invN, m33 = stats[13]*invN;
        const float4 fw = ((const float4*)fwred)[o];
        const float Ef = fw.x*me0 + fw.y*me1 + fw.z*me2 + fw.w*me3;
        const float E2 = fw.x*fw.x*m00 + fw.y*fw.y*m11 + fw.z*fw.z*m22 + fw.w*fw.w*m33
                       + 2.f*(fw.x*fw.y*m01 + fw.x*fw.z*m02 + fw.x*fw.w*m03
                            + fw.y*fw.z*m12 + fw.y*fw.w*m13 + fw.z*fw.w*m23);
        const float a = gamma[o] * rsqrtf(E2 - Ef*Ef + EPS);
        alL[tid] = a;
        beL[tid] = beta[o] - Ef*a;
        fwL[tid] = fw;
    }
    __syncthreads();

    const int p0 = chunk*1024 + tid*4;
    const float* eb = ebuf + (size_t)b*4*HWn;
    const float4 E0 = *(const float4*)(eb + 0*HWn + p0);
    const float4 E1 = *(const float4*)(eb + 1*HWn + p0);
    const float4 E2v = *(const float4*)(eb + 2*HWn + p0);
    const float4 E3 = *(const float4*)(eb + 3*HWn + p0);

    #pragma unroll
    for (int c = 0; c < 8; ++c) {
        const int o = oct*8 + c;
        const float4 fw = fwL[c];
        const float al = alL[c], be = beL[c];
        float f[4];
        f[0] = fw.x*E0.x + fw.y*E1.x + fw.z*E2v.x + fw.w*E3.x;
        f[1] = fw.x*E0.y + fw.y*E1.y + fw.z*E2v.y + fw.w*E3.y;
        f[2] = fw.x*E0.z + fw.y*E1.z + fw.z*E2v.z + fw.w*E3.z;
        f[3] = fw.x*E0.w + fw.y*E1.w + fw.z*E2v.w + fw.w*E3.w;
        const size_t base = (size_t)(b*Cc + o)*HWn + p0;
        const uint2 xu = *(const uint2*)(xbf + base);
        float xa[4];
        xa[0] = bf2f((u16)(xu.x & 0xffff)); xa[1] = bf2f((u16)(xu.x >> 16));
        xa[2] = bf2f((u16)(xu.y & 0xffff)); xa[3] = bf2f((u16)(xu.y >> 16));
        float4 r; float* rp = &r.x;
        #pragma unroll
        for (int j = 0; j < 4; ++j) {
            float z = al*f[j] + be;
            z = fmaxf(z, 0.f);
            rp[j] = xa[j] / (1.f + __expf(-z));
        }
        *(float4*)(out + base) = r;
    }
}

extern "C" void kernel_launch(void* const* d_in, const int* in_sizes, int n_in,
                              void* d_out, int out_size, void* d_ws, size_t ws_size,
                              hipStream_t stream)
{
    const float* x   = (const float*)d_in[0];
    const float* qw  = (const float*)d_in[1];
    const float* kw  = (const float*)d_in[2];
    const float* r_q = (const float*)d_in[3];
    const float* rk0 = (const float*)d_in[4];
    const float* rk1 = (const float*)d_in[5];
    const float* rk2 = (const float*)d_in[6];
    const float* rk3 = (const float*)d_in[7];
    const float* fw  = (const float*)d_in[8];
    const float* gm  = (const float*)d_in[9];
    const float* bt  = (const float*)d_in[10];
    float* out = (float*)d_out;
    float* ws  = (float*)d_ws;

    u16*   t     = (u16*)(ws + T_OFF);          // bf16 t, 33.5 MB
    u16*   xbf   = (u16*)ws + 16777216;         // bf16 x copy, second half of T region
    float* ebuf  = ws + E_OFF;                  // combined e (f32), 1 MB
    float* stats = ws + ST_OFF;
    u16*   Abf   = (u16*)(ws + A_OFF);          // fragment-packed bf16 A
    float* cvec  = ws + CV_OFF;
    float* fwr   = ws + FW_OFF;
    u16*   eh    = (u16*)out;                   // 4 MB bf16 partial planes staged in d_out

    k0_precompute<<<5,    256, 0, stream>>>(qw, kw, rk0, rk1, rk2, rk3, fw, Abf, cvec, fwr, stats);
    k1_mfma      <<<2048, 256, 0, stream>>>(x, Abf, t, xbf);
    k23_fused    <<<1024, 256, 0, stream>>>(t, xbf, r_q, cvec, eh);
    k3b_stats    <<<256,  256, 0, stream>>>(eh, ebuf, stats);
    k5_out       <<<2048, 256, 0, stream>>>(xbf, ebuf, fwr, stats, gm, bt, out);
}